// Round 10
// baseline (1282.099 us; speedup 1.0000x reference)
//
#include <hip/hip_runtime.h>
#include <hip/hip_bf16.h>
#include <stdint.h>

#define T_NUM 1024
#define H_DIM 2048
#define E_NUM 16
#define TOPK 4
#define I_DIM 1408
#define SHI_DIM 2816

typedef __attribute__((ext_vector_type(4))) float f32x4;
typedef __attribute__((ext_vector_type(8))) short bf16x8;

static __device__ __forceinline__ short f2bf(float f) {
    __hip_bfloat16 h = __float2bfloat16(f);
    return __builtin_bit_cast(short, h);
}
static __device__ __forceinline__ float bf2f(short s) {
    return __bfloat162float(__builtin_bit_cast(__hip_bfloat16, s));
}

// ---------------- router: fp32 logits -> softmax -> top4 (+ x -> bf16) ------
__global__ void router_kernel(const float* __restrict__ x, const float* __restrict__ wgate,
                              int* __restrict__ top_e, float* __restrict__ top_w,
                              short* __restrict__ xb) {
    const int t = blockIdx.x;
    const int tid = threadIdx.x;       // 256 threads
    __shared__ float xsh[H_DIM];
    const float* xr = x + (size_t)t * H_DIM;
    for (int h = tid; h < H_DIM; h += 256) xsh[h] = xr[h];
    __syncthreads();

    {   // bf16 copy of x
        short v[8];
        #pragma unroll
        for (int i = 0; i < 8; ++i) v[i] = f2bf(xsh[tid * 8 + i]);
        *reinterpret_cast<bf16x8*>(xb + (size_t)t * H_DIM + tid * 8) = *(bf16x8*)v;
    }

    const int e = tid >> 4;            // 0..15
    const int j = tid & 15;
    const float* wr = wgate + (size_t)e * H_DIM;
    float acc = 0.f;
    for (int h = j; h < H_DIM; h += 16) acc += xsh[h] * wr[h];
    #pragma unroll
    for (int m = 8; m >= 1; m >>= 1) acc += __shfl_down(acc, m, 16);

    __shared__ float logits[E_NUM];
    if (j == 0) logits[e] = acc;
    __syncthreads();

    if (tid == 0) {
        float mx = logits[0];
        #pragma unroll
        for (int i = 1; i < E_NUM; ++i) mx = fmaxf(mx, logits[i]);
        float p[E_NUM]; float s = 0.f;
        #pragma unroll
        for (int i = 0; i < E_NUM; ++i) { p[i] = expf(logits[i] - mx); s += p[i]; }
        const float inv = 1.f / s;
        #pragma unroll
        for (int i = 0; i < E_NUM; ++i) p[i] *= inv;
        for (int k = 0; k < TOPK; ++k) {
            float best = -1.f; int bi = 0;
            #pragma unroll
            for (int i = 0; i < E_NUM; ++i) if (p[i] > best) { best = p[i]; bi = i; }
            top_e[t * TOPK + k] = bi;
            top_w[t * TOPK + k] = best;
            p[bi] = -2.f;
        }
    }
}

// ------- stable bucket sort of 4096 slots by expert (deterministic) -------
__global__ void perm_kernel(const int* __restrict__ top_e,
                            int* __restrict__ offs, int* __restrict__ perm) {
    __shared__ int cnt[256][E_NUM];
    __shared__ int base[E_NUM];
    const int tid = threadIdx.x;
    int c[E_NUM];
    #pragma unroll
    for (int i = 0; i < E_NUM; ++i) c[i] = 0;
    for (int s = tid * 16; s < tid * 16 + 16; ++s) c[top_e[s]]++;
    #pragma unroll
    for (int i = 0; i < E_NUM; ++i) cnt[tid][i] = c[i];
    __syncthreads();
    if (tid < E_NUM) {
        int run = 0;
        for (int b = 0; b < 256; ++b) { int v = cnt[b][tid]; cnt[b][tid] = run; run += v; }
        base[tid] = run;
    }
    __syncthreads();
    if (tid == 0) {
        int run = 0;
        for (int e2 = 0; e2 < E_NUM; ++e2) { int v = base[e2]; base[e2] = run; offs[e2] = run; run += v; }
        offs[E_NUM] = run;
    }
    __syncthreads();
    int run[E_NUM];
    #pragma unroll
    for (int i = 0; i < E_NUM; ++i) run[i] = base[i] + cnt[tid][i];
    for (int s = tid * 16; s < tid * 16 + 16; ++s) {
        int e2 = top_e[s];
        perm[run[e2]++] = s;
    }
}

// ------- SwiGLU combine: act = silu(g) * u  (bf16 elementwise) -------
__global__ void swiglu_kernel(const short* __restrict__ g, const short* __restrict__ u,
                              short* __restrict__ act, int n8) {
    const int i = blockIdx.x * 256 + threadIdx.x;
    if (i >= n8) return;
    bf16x8 gv = *reinterpret_cast<const bf16x8*>(g + (size_t)i * 8);
    bf16x8 uv = *reinterpret_cast<const bf16x8*>(u + (size_t)i * 8);
    short o[8];
    #pragma unroll
    for (int j = 0; j < 8; ++j) {
        float gf = bf2f(gv[j]);
        float uf = bf2f(uv[j]);
        o[j] = f2bf(gf / (1.f + __expf(-gf)) * uf);
    }
    *reinterpret_cast<bf16x8*>(act + (size_t)i * 8) = *(bf16x8*)o;
}

// ------- final combine: out[t][h] += sum_k dr[4t+k][h]  (dr pre-weighted) -------
__global__ void combine_kernel(const short* __restrict__ dr, float* __restrict__ out) {
    const int i = blockIdx.x * 256 + threadIdx.x;   // one per 8 cols of a token
    const int t = i >> 8;                            // H_DIM/8 = 256
    const int h8 = (i & 255) * 8;
    float s[8];
    f32x4 o0 = *reinterpret_cast<const f32x4*>(out + (size_t)t * H_DIM + h8);
    f32x4 o1 = *reinterpret_cast<const f32x4*>(out + (size_t)t * H_DIM + h8 + 4);
    #pragma unroll
    for (int j = 0; j < 4; ++j) { s[j] = o0[j]; s[4 + j] = o1[j]; }
    #pragma unroll
    for (int k = 0; k < TOPK; ++k) {
        bf16x8 v = *reinterpret_cast<const bf16x8*>(dr + ((size_t)(t * TOPK + k)) * H_DIM + h8);
        #pragma unroll
        for (int j = 0; j < 8; ++j) s[j] += bf2f(v[j]);
    }
    f32x4 r0 = { s[0], s[1], s[2], s[3] };
    f32x4 r1 = { s[4], s[5], s[6], s[7] };
    *reinterpret_cast<f32x4*>(out + (size_t)t * H_DIM + h8) = r0;
    *reinterpret_cast<f32x4*>(out + (size_t)t * H_DIM + h8 + 4) = r1;
}

// ---- barrier-free 4-wave GEMM: block = 4 waves sharing one 64-col B strip ----
// Each wave owns MW x 64 of the output; B loads are identical across waves
// (L1/MSHR-served), A/B go straight to registers; NO LDS, NO barriers.
// A bf16 [rows][K] k-contig; B f32 [K][N] native (cvt in register).
// MODE 0: routed gate|up : A=xb gathered; ntt<nsplit ? wg[e]->Out1 : wu[e]->Out2 (bf16)
// MODE 1: shared gate|up : A=xb dense;    ntt<nsplit ? sg->Out1 : su->Out2 (bf16)
// MODE 2: routed down    : A=act_r gathered; B=wd[e]; store bf16 dr[slot] = w*v
// MODE 3: shared down    : A=act_s dense;    B=sd;    store f32 Out1[row]
template<int MODE, int MW>
__global__ __launch_bounds__(256, 3) void gemm_wave4(
    const short* __restrict__ A,
    const float* __restrict__ B1g, const float* __restrict__ B2g,
    void* __restrict__ Out1v, void* __restrict__ Out2v,
    const int* __restrict__ perm, const int* __restrict__ offs,
    const float* __restrict__ top_w, int nmt, int nnt, int nsplit)
{
    constexpr int KD  = (MODE == 0 || MODE == 1) ? H_DIM : (MODE == 2 ? I_DIM : SHI_DIM);
    constexpr int LDB = (MODE == 0) ? I_DIM : (MODE == 1) ? SHI_DIM : H_DIM;
    constexpr int LDO = LDB;
    constexpr int NK  = KD / 32;
    constexpr int MF  = MW / 16;          // A fragments per wave (2 or 4)
    constexpr int MB  = MW * 4;           // block M rows

    const int tid  = threadIdx.x;
    const int lane = tid & 63;
    const int wid  = tid >> 6;            // wave id 0..3

    // bijective XCD swizzle, mt innermost
    int wgid = blockIdx.x;
    {
        const int nwg = gridDim.x;
        const int qq = nwg >> 3, rr = nwg & 7;
        const int xcd = wgid & 7, lin = wgid >> 3;
        wgid = (xcd < rr ? xcd * (qq + 1) : rr * (qq + 1) + (xcd - rr) * qq) + lin;
    }
    const int mt  = wgid % nmt;
    const int ntt = (wgid / nmt) % nnt;
    const int e   = wgid / (nmt * nnt);

    int off = 0, cnt = T_NUM;
    const float* B1 = B1g;
    const float* B2 = B2g;
    if constexpr (MODE == 0) {
        off = offs[e]; cnt = offs[e + 1] - off;
        if (mt * MB >= cnt) return;
        B1 = B1g + (size_t)e * H_DIM * I_DIM;
        B2 = B2g + (size_t)e * H_DIM * I_DIM;
    }
    if constexpr (MODE == 2) {
        off = offs[e]; cnt = offs[e + 1] - off;
        if (mt * MB >= cnt) return;
        B1 = B1g + (size_t)e * I_DIM * H_DIM;
    }
    const float* Bsel = (ntt < nsplit) ? B1 : B2;
    const int ncol = (ntt % nsplit) * 64;
    const int rb = mt * MB + wid * MW;    // this wave's row base

    // A row pointers, one per m-fragment (row = rb + mi*16 + (lane&15))
    const short* Ap[MF];
    #pragma unroll
    for (int mi = 0; mi < MF; ++mi) {
        int gm = rb + mi * 16 + (lane & 15);
        int ra;
        if constexpr (MODE == 0) {
            ra = perm[off + (gm < cnt ? gm : cnt - 1)] >> 2;
        } else if constexpr (MODE == 2) {
            ra = perm[off + (gm < cnt ? gm : cnt - 1)];
        } else {
            ra = gm;
        }
        Ap[mi] = A + (size_t)ra * KD;
    }

    const int koff = (lane >> 4) * 8;                    // 0,8,16,24
    const float* Bp = Bsel + (size_t)koff * LDB + ncol + (lane & 15);

    f32x4 acc[MF][4];
    #pragma unroll
    for (int i = 0; i < MF; ++i)
        #pragma unroll
        for (int j = 0; j < 4; ++j) acc[i][j] = (f32x4)0.f;

    for (int kt = 0; kt < NK; ++kt) {
        const int k0 = kt * 32;
        bf16x8 af[MF];
        #pragma unroll
        for (int mi = 0; mi < MF; ++mi)
            af[mi] = *reinterpret_cast<const bf16x8*>(Ap[mi] + k0 + koff);
        const float* bp = Bp + (size_t)k0 * LDB;
        bf16x8 b0, b1, b2, b3;
        #pragma unroll
        for (int j = 0; j < 8; ++j) {
            const float* r = bp + (size_t)j * LDB;
            b0[j] = f2bf(r[0]);
            b1[j] = f2bf(r[16]);
            b2[j] = f2bf(r[32]);
            b3[j] = f2bf(r[48]);
        }
        #pragma unroll
        for (int mi = 0; mi < MF; ++mi) {
            acc[mi][0] = __builtin_amdgcn_mfma_f32_16x16x32_bf16(af[mi], b0, acc[mi][0], 0, 0, 0);
            acc[mi][1] = __builtin_amdgcn_mfma_f32_16x16x32_bf16(af[mi], b1, acc[mi][1], 0, 0, 0);
            acc[mi][2] = __builtin_amdgcn_mfma_f32_16x16x32_bf16(af[mi], b2, acc[mi][2], 0, 0, 0);
            acc[mi][3] = __builtin_amdgcn_mfma_f32_16x16x32_bf16(af[mi], b3, acc[mi][3], 0, 0, 0);
        }
    }

    // epilogue: C layout row=(lane>>4)*4+j, col=lane&15 within each 16x16 tile
    #pragma unroll
    for (int mi = 0; mi < MF; ++mi) {
        #pragma unroll
        for (int j = 0; j < 4; ++j) {
            const int r = rb + mi * 16 + (lane >> 4) * 4 + j;
            if constexpr (MODE == 0 || MODE == 2) { if (r >= cnt) continue; }
            int orow; float w = 1.f;
            if constexpr (MODE == 0) {
                orow = perm[off + r];
            } else if constexpr (MODE == 2) {
                int s = perm[off + r]; orow = s; w = top_w[s];
            } else {
                orow = r;
            }
            #pragma unroll
            for (int nt2 = 0; nt2 < 4; ++nt2) {
                const int n = ncol + nt2 * 16 + (lane & 15);
                const float v = acc[mi][nt2][j];
                if constexpr (MODE == 0 || MODE == 1) {
                    short* o = (short*)((ntt < nsplit) ? Out1v : Out2v);
                    o[(size_t)orow * LDO + n] = f2bf(v);
                } else if constexpr (MODE == 2) {
                    ((short*)Out1v)[(size_t)orow * LDO + n] = f2bf(v * w);
                } else {
                    ((float*)Out1v)[(size_t)orow * LDO + n] = v;
                }
            }
        }
    }
}

extern "C" void kernel_launch(void* const* d_in, const int* in_sizes, int n_in,
                              void* d_out, int out_size, void* d_ws, size_t ws_size,
                              hipStream_t stream) {
    const float* x     = (const float*)d_in[0];
    const float* wgate = (const float*)d_in[1];
    const float* wg    = (const float*)d_in[2];
    const float* wu    = (const float*)d_in[3];
    const float* wd    = (const float*)d_in[4];
    const float* sg    = (const float*)d_in[5];
    const float* su    = (const float*)d_in[6];
    const float* sd    = (const float*)d_in[7];
    float* out = (float*)d_out;

    uintptr_t p = (uintptr_t)d_ws;
    auto alloc = [&](size_t bytes) {
        p = (p + 255) & ~(uintptr_t)255;
        void* r = (void*)p; p += bytes; return r;
    };
    int*   top_e = (int*)alloc((size_t)T_NUM * TOPK * sizeof(int));
    float* top_w = (float*)alloc((size_t)T_NUM * TOPK * sizeof(float));
    int*   offs  = (int*)alloc((E_NUM + 1) * sizeof(int));
    int*   perm  = (int*)alloc((size_t)T_NUM * TOPK * sizeof(int));
    short* xb    = (short*)alloc((size_t)T_NUM * H_DIM * 2);
    short* g_r   = (short*)alloc((size_t)T_NUM * TOPK * I_DIM * 2);
    short* u_r   = (short*)alloc((size_t)T_NUM * TOPK * I_DIM * 2);
    short* act_r = (short*)alloc((size_t)T_NUM * TOPK * I_DIM * 2);
    short* g_s   = (short*)alloc((size_t)T_NUM * SHI_DIM * 2);
    short* u_s   = (short*)alloc((size_t)T_NUM * SHI_DIM * 2);
    short* act_s = (short*)alloc((size_t)T_NUM * SHI_DIM * 2);
    short* dr    = (short*)alloc((size_t)T_NUM * TOPK * H_DIM * 2);   // 16.8 MB

    router_kernel<<<T_NUM, 256, 0, stream>>>(x, wgate, top_e, top_w, xb);
    perm_kernel<<<1, 256, 0, stream>>>(top_e, offs, perm);

    const int nnI = I_DIM / 64;     // 22
    const int nnH = H_DIM / 64;     // 32
    const int nnS = SHI_DIM / 64;   // 44

    // shared gate|up: MW=32 (block 128M), nmt=8. grid 8 * 88 = 704
    gemm_wave4<1, 32><<<8 * (2 * nnS), 256, 0, stream>>>(
        xb, sg, su, g_s, u_s, nullptr, nullptr, nullptr, 8, 2 * nnS, nnS);
    swiglu_kernel<<<(T_NUM * SHI_DIM / 8 + 255) / 256, 256, 0, stream>>>(
        g_s, u_s, act_s, T_NUM * SHI_DIM / 8);
    // shared down: MW=32, nmt=8. grid 8 * 32 = 256 (plain stores init out)
    gemm_wave4<3, 32><<<8 * nnH, 256, 0, stream>>>(
        act_s, sd, nullptr, out, nullptr, nullptr, nullptr, nullptr, 8, nnH, nnH);

    // routed gate|up per expert: MW=64 (block 256M), nmt=4. grid 4 * 44 * 16 = 2816
    gemm_wave4<0, 64><<<4 * (2 * nnI) * E_NUM, 256, 0, stream>>>(
        xb, wg, wu, g_r, u_r, perm, offs, nullptr, 4, 2 * nnI, nnI);
    swiglu_kernel<<<(T_NUM * TOPK * I_DIM / 8 + 255) / 256, 256, 0, stream>>>(
        g_r, u_r, act_r, T_NUM * TOPK * I_DIM / 8);
    // routed down per expert: MW=64, nmt=4. grid 4 * 32 * 16 = 2048
    gemm_wave4<2, 64><<<4 * nnH * E_NUM, 256, 0, stream>>>(
        act_r, wd, nullptr, dr, nullptr, perm, offs, top_w, 4, nnH, nnH);
    // out[t] += sum_k dr[4t+k]
    combine_kernel<<<T_NUM * H_DIM / 8 / 256, 256, 0, stream>>>(dr, out);
}

// Round 11
// 782.431 us; speedup vs baseline: 1.6386x; 1.6386x over previous
//
#include <hip/hip_runtime.h>
#include <hip/hip_bf16.h>
#include <stdint.h>

#define T_NUM 1024
#define H_DIM 2048
#define E_NUM 16
#define TOPK 4
#define I_DIM 1408
#define SHI_DIM 2816

typedef __attribute__((ext_vector_type(4))) float f32x4;
typedef __attribute__((ext_vector_type(8))) short bf16x8;

static __device__ __forceinline__ short f2bf(float f) {
    __hip_bfloat16 h = __float2bfloat16(f);
    return __builtin_bit_cast(short, h);
}
static __device__ __forceinline__ float bf2f(short s) {
    return __bfloat162float(__builtin_bit_cast(__hip_bfloat16, s));
}

// ---------------- router: fp32 logits -> softmax -> top4 (+ x -> bf16) ------
__global__ void router_kernel(const float* __restrict__ x, const float* __restrict__ wgate,
                              int* __restrict__ top_e, float* __restrict__ top_w,
                              short* __restrict__ xb) {
    const int t = blockIdx.x;
    const int tid = threadIdx.x;       // 256 threads
    __shared__ float xsh[H_DIM];
    const float* xr = x + (size_t)t * H_DIM;
    for (int h = tid; h < H_DIM; h += 256) xsh[h] = xr[h];
    __syncthreads();

    {   // bf16 copy of x
        short v[8];
        #pragma unroll
        for (int i = 0; i < 8; ++i) v[i] = f2bf(xsh[tid * 8 + i]);
        *reinterpret_cast<bf16x8*>(xb + (size_t)t * H_DIM + tid * 8) = *(bf16x8*)v;
    }

    const int e = tid >> 4;            // 0..15
    const int j = tid & 15;
    const float* wr = wgate + (size_t)e * H_DIM;
    float acc = 0.f;
    for (int h = j; h < H_DIM; h += 16) acc += xsh[h] * wr[h];
    #pragma unroll
    for (int m = 8; m >= 1; m >>= 1) acc += __shfl_down(acc, m, 16);

    __shared__ float logits[E_NUM];
    if (j == 0) logits[e] = acc;
    __syncthreads();

    if (tid == 0) {
        float mx = logits[0];
        #pragma unroll
        for (int i = 1; i < E_NUM; ++i) mx = fmaxf(mx, logits[i]);
        float p[E_NUM]; float s = 0.f;
        #pragma unroll
        for (int i = 0; i < E_NUM; ++i) { p[i] = expf(logits[i] - mx); s += p[i]; }
        const float inv = 1.f / s;
        #pragma unroll
        for (int i = 0; i < E_NUM; ++i) p[i] *= inv;
        for (int k = 0; k < TOPK; ++k) {
            float best = -1.f; int bi = 0;
            #pragma unroll
            for (int i = 0; i < E_NUM; ++i) if (p[i] > best) { best = p[i]; bi = i; }
            top_e[t * TOPK + k] = bi;
            top_w[t * TOPK + k] = best;
            p[bi] = -2.f;
        }
    }
}

// ------- stable bucket sort of 4096 slots by expert (deterministic) -------
__global__ void perm_kernel(const int* __restrict__ top_e,
                            int* __restrict__ offs, int* __restrict__ perm) {
    __shared__ int cnt[256][E_NUM];
    __shared__ int base[E_NUM];
    const int tid = threadIdx.x;
    int c[E_NUM];
    #pragma unroll
    for (int i = 0; i < E_NUM; ++i) c[i] = 0;
    for (int s = tid * 16; s < tid * 16 + 16; ++s) c[top_e[s]]++;
    #pragma unroll
    for (int i = 0; i < E_NUM; ++i) cnt[tid][i] = c[i];
    __syncthreads();
    if (tid < E_NUM) {
        int run = 0;
        for (int b = 0; b < 256; ++b) { int v = cnt[b][tid]; cnt[b][tid] = run; run += v; }
        base[tid] = run;
    }
    __syncthreads();
    if (tid == 0) {
        int run = 0;
        for (int e2 = 0; e2 < E_NUM; ++e2) { int v = base[e2]; base[e2] = run; offs[e2] = run; run += v; }
        offs[E_NUM] = run;
    }
    __syncthreads();
    int run[E_NUM];
    #pragma unroll
    for (int i = 0; i < E_NUM; ++i) run[i] = base[i] + cnt[tid][i];
    for (int s = tid * 16; s < tid * 16 + 16; ++s) {
        int e2 = top_e[s];
        perm[run[e2]++] = s;
    }
}

// ------- final combine: out[t][h] += sum_k dr[4t+k][h]  (dr pre-weighted) -------
__global__ void combine_kernel(const short* __restrict__ dr, float* __restrict__ out) {
    const int i = blockIdx.x * 256 + threadIdx.x;   // one per 8 cols of a token
    const int t = i >> 8;                            // H_DIM/8 = 256
    const int h8 = (i & 255) * 8;
    float s[8];
    f32x4 o0 = *reinterpret_cast<const f32x4*>(out + (size_t)t * H_DIM + h8);
    f32x4 o1 = *reinterpret_cast<const f32x4*>(out + (size_t)t * H_DIM + h8 + 4);
    #pragma unroll
    for (int j = 0; j < 4; ++j) { s[j] = o0[j]; s[4 + j] = o1[j]; }
    #pragma unroll
    for (int k = 0; k < TOPK; ++k) {
        bf16x8 v = *reinterpret_cast<const bf16x8*>(dr + ((size_t)(t * TOPK + k)) * H_DIM + h8);
        #pragma unroll
        for (int j = 0; j < 8; ++j) s[j] += bf2f(v[j]);
    }
    f32x4 r0 = { s[0], s[1], s[2], s[3] };
    f32x4 r1 = { s[4], s[5], s[6], s[7] };
    *reinterpret_cast<f32x4*>(out + (size_t)t * H_DIM + h8) = r0;
    *reinterpret_cast<f32x4*>(out + (size_t)t * H_DIM + h8 + 4) = r1;
}

// ---- fused gate+up+SwiGLU: 1 wave/block, 32M x 64N, no LDS, no barriers ----
// A bf16 [rows][K=H] k-contig; Bg,Bu f32 [K][N] native (cvt in register).
// MODE 0: routed (A=xb gathered via perm; act out per slot)
// MODE 1: shared (A=xb dense; act out per token)
template<int MODE>
__global__ __launch_bounds__(64) void gemm_gu(
    const short* __restrict__ A,
    const float* __restrict__ Bg_, const float* __restrict__ Bu_,
    short* __restrict__ Act,
    const int* __restrict__ perm, const int* __restrict__ offs,
    int nmt, int nnt)
{
    constexpr int KD  = H_DIM;
    constexpr int LDB = (MODE == 0) ? I_DIM : SHI_DIM;
    constexpr int NK  = KD / 32;

    const int lane = threadIdx.x;   // 64

    // bijective XCD swizzle, mt innermost (same-strip readers -> same XCD, concurrent)
    int wgid = blockIdx.x;
    {
        const int nwg = gridDim.x;
        const int qq = nwg >> 3, rr = nwg & 7;
        const int xcd = wgid & 7, lin = wgid >> 3;
        wgid = (xcd < rr ? xcd * (qq + 1) : rr * (qq + 1) + (xcd - rr) * qq) + lin;
    }
    const int mt  = wgid % nmt;
    const int ntt = (wgid / nmt) % nnt;
    const int e   = wgid / (nmt * nnt);

    int off = 0, cnt = T_NUM;
    const float* Bg = Bg_;
    const float* Bu = Bu_;
    if constexpr (MODE == 0) {
        off = offs[e]; cnt = offs[e + 1] - off;
        if (mt * 32 >= cnt) return;
        Bg = Bg_ + (size_t)e * H_DIM * I_DIM;
        Bu = Bu_ + (size_t)e * H_DIM * I_DIM;
    }
    const int ncol = ntt * 64;

    // A row pointers (row = mt*32 + mi*16 + (lane&15))
    const short* Ap0;
    const short* Ap1;
    {
        int gm0 = mt * 32 + (lane & 15);
        int gm1 = gm0 + 16;
        int ra0, ra1;
        if constexpr (MODE == 0) {
            ra0 = perm[off + (gm0 < cnt ? gm0 : cnt - 1)] >> 2;
            ra1 = perm[off + (gm1 < cnt ? gm1 : cnt - 1)] >> 2;
        } else {
            ra0 = gm0; ra1 = gm1;
        }
        Ap0 = A + (size_t)ra0 * KD;
        Ap1 = A + (size_t)ra1 * KD;
    }

    const int koff = (lane >> 4) * 8;                    // 0,8,16,24
    const float* Bpg = Bg + (size_t)koff * LDB + ncol + (lane & 15);
    const float* Bpu = Bu + (size_t)koff * LDB + ncol + (lane & 15);

    f32x4 ag[2][4], au[2][4];
    #pragma unroll
    for (int i = 0; i < 2; ++i)
        #pragma unroll
        for (int j = 0; j < 4; ++j) { ag[i][j] = (f32x4)0.f; au[i][j] = (f32x4)0.f; }

    for (int kt = 0; kt < NK; ++kt) {
        const int k0 = kt * 32;
        bf16x8 a0 = *reinterpret_cast<const bf16x8*>(Ap0 + k0 + koff);
        bf16x8 a1 = *reinterpret_cast<const bf16x8*>(Ap1 + k0 + koff);
        // gate strip
        {
            const float* bp = Bpg + (size_t)k0 * LDB;
            bf16x8 b0, b1, b2, b3;
            #pragma unroll
            for (int j = 0; j < 8; ++j) {
                const float* r = bp + (size_t)j * LDB;
                b0[j] = f2bf(r[0]);
                b1[j] = f2bf(r[16]);
                b2[j] = f2bf(r[32]);
                b3[j] = f2bf(r[48]);
            }
            ag[0][0] = __builtin_amdgcn_mfma_f32_16x16x32_bf16(a0, b0, ag[0][0], 0, 0, 0);
            ag[1][0] = __builtin_amdgcn_mfma_f32_16x16x32_bf16(a1, b0, ag[1][0], 0, 0, 0);
            ag[0][1] = __builtin_amdgcn_mfma_f32_16x16x32_bf16(a0, b1, ag[0][1], 0, 0, 0);
            ag[1][1] = __builtin_amdgcn_mfma_f32_16x16x32_bf16(a1, b1, ag[1][1], 0, 0, 0);
            ag[0][2] = __builtin_amdgcn_mfma_f32_16x16x32_bf16(a0, b2, ag[0][2], 0, 0, 0);
            ag[1][2] = __builtin_amdgcn_mfma_f32_16x16x32_bf16(a1, b2, ag[1][2], 0, 0, 0);
            ag[0][3] = __builtin_amdgcn_mfma_f32_16x16x32_bf16(a0, b3, ag[0][3], 0, 0, 0);
            ag[1][3] = __builtin_amdgcn_mfma_f32_16x16x32_bf16(a1, b3, ag[1][3], 0, 0, 0);
        }
        // up strip
        {
            const float* bp = Bpu + (size_t)k0 * LDB;
            bf16x8 b0, b1, b2, b3;
            #pragma unroll
            for (int j = 0; j < 8; ++j) {
                const float* r = bp + (size_t)j * LDB;
                b0[j] = f2bf(r[0]);
                b1[j] = f2bf(r[16]);
                b2[j] = f2bf(r[32]);
                b3[j] = f2bf(r[48]);
            }
            au[0][0] = __builtin_amdgcn_mfma_f32_16x16x32_bf16(a0, b0, au[0][0], 0, 0, 0);
            au[1][0] = __builtin_amdgcn_mfma_f32_16x16x32_bf16(a1, b0, au[1][0], 0, 0, 0);
            au[0][1] = __builtin_amdgcn_mfma_f32_16x16x32_bf16(a0, b1, au[0][1], 0, 0, 0);
            au[1][1] = __builtin_amdgcn_mfma_f32_16x16x32_bf16(a1, b1, au[1][1], 0, 0, 0);
            au[0][2] = __builtin_amdgcn_mfma_f32_16x16x32_bf16(a0, b2, au[0][2], 0, 0, 0);
            au[1][2] = __builtin_amdgcn_mfma_f32_16x16x32_bf16(a1, b2, au[1][2], 0, 0, 0);
            au[0][3] = __builtin_amdgcn_mfma_f32_16x16x32_bf16(a0, b3, au[0][3], 0, 0, 0);
            au[1][3] = __builtin_amdgcn_mfma_f32_16x16x32_bf16(a1, b3, au[1][3], 0, 0, 0);
        }
    }

    // epilogue: act = silu(g)*u, bf16
    #pragma unroll
    for (int mi = 0; mi < 2; ++mi) {
        #pragma unroll
        for (int j = 0; j < 4; ++j) {
            const int r = mt * 32 + mi * 16 + (lane >> 4) * 4 + j;
            if constexpr (MODE == 0) { if (r >= cnt) continue; }
            int orow;
            if constexpr (MODE == 0) orow = perm[off + r];
            else                     orow = r;
            #pragma unroll
            for (int nt2 = 0; nt2 < 4; ++nt2) {
                const int n = ncol + nt2 * 16 + (lane & 15);
                const float g = ag[mi][nt2][j];
                const float u = au[mi][nt2][j];
                Act[(size_t)orow * LDB + n] = f2bf(g / (1.f + __expf(-g)) * u);
            }
        }
    }
}

// ---- down-proj: 1 wave/block, 64M x 64N, no LDS, no barriers ----
// A bf16 [rows][K] k-contig; B f32 [K][H] native.
// MODE 2: routed (A=act_r gathered; dr[slot] = w * v, bf16)
// MODE 3: shared (A=act_s dense;    out f32 plain store)
template<int MODE>
__global__ __launch_bounds__(64) void gemm_dn(
    const short* __restrict__ A,
    const float* __restrict__ B_,
    void* __restrict__ Outv,
    const int* __restrict__ perm, const int* __restrict__ offs,
    const float* __restrict__ top_w, int nmt, int nnt)
{
    constexpr int KD  = (MODE == 2) ? I_DIM : SHI_DIM;
    constexpr int LDB = H_DIM;
    constexpr int NK  = KD / 32;

    const int lane = threadIdx.x;   // 64

    int wgid = blockIdx.x;
    {
        const int nwg = gridDim.x;
        const int qq = nwg >> 3, rr = nwg & 7;
        const int xcd = wgid & 7, lin = wgid >> 3;
        wgid = (xcd < rr ? xcd * (qq + 1) : rr * (qq + 1) + (xcd - rr) * qq) + lin;
    }
    const int mt  = wgid % nmt;
    const int ntt = (wgid / nmt) % nnt;
    const int e   = wgid / (nmt * nnt);

    int off = 0, cnt = T_NUM;
    const float* B = B_;
    if constexpr (MODE == 2) {
        off = offs[e]; cnt = offs[e + 1] - off;
        if (mt * 64 >= cnt) return;
        B = B_ + (size_t)e * I_DIM * H_DIM;
    }
    const int ncol = ntt * 64;

    const short* Ap[4];
    #pragma unroll
    for (int mi = 0; mi < 4; ++mi) {
        int gm = mt * 64 + mi * 16 + (lane & 15);
        int ra;
        if constexpr (MODE == 2) ra = perm[off + (gm < cnt ? gm : cnt - 1)];
        else                     ra = gm;
        Ap[mi] = A + (size_t)ra * KD;
    }

    const int koff = (lane >> 4) * 8;
    const float* Bp = B + (size_t)koff * LDB + ncol + (lane & 15);

    f32x4 acc[4][4];
    #pragma unroll
    for (int i = 0; i < 4; ++i)
        #pragma unroll
        for (int j = 0; j < 4; ++j) acc[i][j] = (f32x4)0.f;

    for (int kt = 0; kt < NK; ++kt) {
        const int k0 = kt * 32;
        bf16x8 af[4];
        #pragma unroll
        for (int mi = 0; mi < 4; ++mi)
            af[mi] = *reinterpret_cast<const bf16x8*>(Ap[mi] + k0 + koff);
        const float* bp = Bp + (size_t)k0 * LDB;
        bf16x8 b0, b1, b2, b3;
        #pragma unroll
        for (int j = 0; j < 8; ++j) {
            const float* r = bp + (size_t)j * LDB;
            b0[j] = f2bf(r[0]);
            b1[j] = f2bf(r[16]);
            b2[j] = f2bf(r[32]);
            b3[j] = f2bf(r[48]);
        }
        #pragma unroll
        for (int mi = 0; mi < 4; ++mi) {
            acc[mi][0] = __builtin_amdgcn_mfma_f32_16x16x32_bf16(af[mi], b0, acc[mi][0], 0, 0, 0);
            acc[mi][1] = __builtin_amdgcn_mfma_f32_16x16x32_bf16(af[mi], b1, acc[mi][1], 0, 0, 0);
            acc[mi][2] = __builtin_amdgcn_mfma_f32_16x16x32_bf16(af[mi], b2, acc[mi][2], 0, 0, 0);
            acc[mi][3] = __builtin_amdgcn_mfma_f32_16x16x32_bf16(af[mi], b3, acc[mi][3], 0, 0, 0);
        }
    }

    #pragma unroll
    for (int mi = 0; mi < 4; ++mi) {
        #pragma unroll
        for (int j = 0; j < 4; ++j) {
            const int r = mt * 64 + mi * 16 + (lane >> 4) * 4 + j;
            if constexpr (MODE == 2) { if (r >= cnt) continue; }
            #pragma unroll
            for (int nt2 = 0; nt2 < 4; ++nt2) {
                const int n = ncol + nt2 * 16 + (lane & 15);
                const float v = acc[mi][nt2][j];
                if constexpr (MODE == 2) {
                    int s = perm[off + r];
                    ((short*)Outv)[(size_t)s * H_DIM + n] = f2bf(v * top_w[s]);
                } else {
                    ((float*)Outv)[(size_t)r * H_DIM + n] = v;
                }
            }
        }
    }
}

extern "C" void kernel_launch(void* const* d_in, const int* in_sizes, int n_in,
                              void* d_out, int out_size, void* d_ws, size_t ws_size,
                              hipStream_t stream) {
    const float* x     = (const float*)d_in[0];
    const float* wgate = (const float*)d_in[1];
    const float* wg    = (const float*)d_in[2];
    const float* wu    = (const float*)d_in[3];
    const float* wd    = (const float*)d_in[4];
    const float* sg    = (const float*)d_in[5];
    const float* su    = (const float*)d_in[6];
    const float* sd    = (const float*)d_in[7];
    float* out = (float*)d_out;

    uintptr_t p = (uintptr_t)d_ws;
    auto alloc = [&](size_t bytes) {
        p = (p + 255) & ~(uintptr_t)255;
        void* r = (void*)p; p += bytes; return r;
    };
    int*   top_e = (int*)alloc((size_t)T_NUM * TOPK * sizeof(int));
    float* top_w = (float*)alloc((size_t)T_NUM * TOPK * sizeof(float));
    int*   offs  = (int*)alloc((E_NUM + 1) * sizeof(int));
    int*   perm  = (int*)alloc((size_t)T_NUM * TOPK * sizeof(int));
    short* xb    = (short*)alloc((size_t)T_NUM * H_DIM * 2);
    short* act_r = (short*)alloc((size_t)T_NUM * TOPK * I_DIM * 2);
    short* act_s = (short*)alloc((size_t)T_NUM * SHI_DIM * 2);
    short* dr    = (short*)alloc((size_t)T_NUM * TOPK * H_DIM * 2);   // 16.8 MB

    router_kernel<<<T_NUM, 256, 0, stream>>>(x, wgate, top_e, top_w, xb);
    perm_kernel<<<1, 256, 0, stream>>>(top_e, offs, perm);

    // shared fused gate+up+swiglu: nmt=32 (1024/32), nnt=44. grid 1408
    gemm_gu<1><<<32 * (SHI_DIM / 64), 64, 0, stream>>>(
        xb, sg, su, act_s, nullptr, nullptr, 32, SHI_DIM / 64);
    // shared down: nmt=16 (1024/64), nnt=32. grid 512 (plain stores init out)
    gemm_dn<3><<<16 * (H_DIM / 64), 64, 0, stream>>>(
        act_s, sd, out, nullptr, nullptr, nullptr, 16, H_DIM / 64);

    // routed fused gate+up+swiglu per expert: nmt=32, nnt=22. grid 11264
    gemm_gu<0><<<32 * (I_DIM / 64) * E_NUM, 64, 0, stream>>>(
        xb, wg, wu, act_r, perm, offs, 32, I_DIM / 64);
    // routed down per expert: nmt=16, nnt=32. grid 8192
    gemm_dn<2><<<16 * (H_DIM / 64) * E_NUM, 64, 0, stream>>>(
        act_r, wd, dr, perm, offs, top_w, 16, H_DIM / 64);
    // out[t] += sum_k dr[4t+k]
    combine_kernel<<<T_NUM * H_DIM / 8 / 256, 256, 0, stream>>>(dr, out);
}